// Round 2
// baseline (155.275 us; speedup 1.0000x reference)
//
#include <hip/hip_runtime.h>
#include <math.h>

// fab_penalty_ls_curve — R6: rolling window, but sized to the register budget.
// R5 post-mortem: h[5][8] ring => 108 VGPRs => 4 waves/SIMD (occ 19%) AND only
// 3 loads/iter with load->use dependency => MLP collapse => VALUBusy 30%, 67us.
// R6 keeps vertical register reuse but at 1 col/thread: exactly the 13 live
// stencil values rotate through named registers (SSA renaming, no movs).
// Per row advance: 5 INDEPENDENT scalar loads (rows i+3 @ j, i+2 @ j+-1,
// i+1 @ j+-2), prefetched before the current point's ~50-inst compute.
// Coalescing: consecutive threads = consecutive cols. Grid back to 4096 blocks.
// __launch_bounds__(256,8) pins VGPR<=64 => 8 waves/SIMD.
// Loads: 13/point (R4) -> 5/point; inst/point ~125 -> ~58.
// Reduction plumbing unchanged (plain partial stores -> finish kernel;
// device-atomic finish was R2/R3's 3x regression). Mirror-half x2 trick kept.
// Assumes Wn % BLOCK_X == 0 and Hn % ROWS_PER == 0 (4096x4096 input).

#define BLOCK_X 256
#define ROWS_PER 16

// atan(v / c) with v > 0, given rv ~= 1/v (reused from k = num*rv^3).
// Max abs error ~1e-5 rad; error budget is ~1e3x larger (2% on the sum).
__device__ __forceinline__ float fast_atan_ratio(float v, float c, float rv)
{
    const float rc = __builtin_amdgcn_rcpf(c);
    const float q  = v * rc;        // v/c (sign = sign(c))
    const float iq = c * rv;        // c/v = 1/q, no extra rcp
    const bool  big = fabsf(q) > 1.0f;
    const float t  = big ? iq : q;
    const float s  = t * t;
    float p = fmaf(s, -0.01172120f, 0.05265332f);
    p = fmaf(s, p, -0.11643287f);
    p = fmaf(s, p,  0.19354346f);
    p = fmaf(s, p, -0.33262347f);
    p = fmaf(s, p,  0.99997726f);
    const float at = p * t;
    const float hp = copysignf(1.57079632679f, q);
    return big ? (hp - at) : at;    // atan(q) = sign(q)*pi/2 - atan(1/q), |q|>1
}

// One strip of ROWS_PER points for one column. YB=false: pure interior rows,
// three streaming row pointers. YB=true (first/last gy blocks only): clamped
// row indices + one-sided scales. Window state (13 floats) in named registers:
//   a2 a1 a0 b1 b2 : col j    at rows i-2..i+2
//   wN w0 wS       : col jm   at rows i-1..i+1
//   eN e0 eS       : col cjp  at rows i-1..i+1
//   ww  ee         : cols jmm / cjpp at row i
template<bool YB>
__device__ __forceinline__ float strip_compute(
    const float* __restrict__ eps, int Hn, int Wn, int i0,
    int j, int jm, int jmm, int cjp, int cjpp,
    float rd, float rd2, float syj, float sym, bool jz)
{
    const float SC     = 1e-12f;
    const float FLOORV = (float)(1e-32 / 6.0);
    const float pi_d   = 3.14159265358979323846f / 1.1f;

    auto rp = [&](int t) -> const float* {
        int tt = t;
        if (YB) { tt = tt < 0 ? 0 : tt; tt = tt > Hn - 1 ? Hn - 1 : tt; }
        return eps + (size_t)tt * (size_t)Wn;
    };

    // preload the window for point i0 (13 independent loads)
    float a2 = rp(i0 - 2)[j],   a1 = rp(i0 - 1)[j],  a0 = rp(i0)[j];
    float b1 = rp(i0 + 1)[j],   b2 = rp(i0 + 2)[j];
    float wN = rp(i0 - 1)[jm],  w0 = rp(i0)[jm],     wS = rp(i0 + 1)[jm];
    float eN = rp(i0 - 1)[cjp], e0 = rp(i0)[cjp],    eS = rp(i0 + 1)[cjp];
    float ww = rp(i0)[jmm],     ee = rp(i0)[cjpp];

    // streaming row pointers (interior path only)
    const float* pj = eps + (size_t)(i0 + 3) * (size_t)Wn;  // row i+3 (col j)
    const float* p2 = eps + (size_t)(i0 + 2) * (size_t)Wn;  // row i+2 (jm, cjp)
    const float* p1 = eps + (size_t)(i0 + 1) * (size_t)Wn;  // row i+1 (jmm, cjpp)

    float acc = 0.0f;
    #pragma unroll
    for (int r = 0; r < ROWS_PER; ++r) {
        const int i = i0 + r;

        // prefetch next point's incoming window rows (5 independent loads),
        // issued BEFORE this point's compute so latency hides under the math.
        float nb2 = 0.0f, nwS = 0.0f, neS = 0.0f, nww = 0.0f, nee = 0.0f;
        if (r + 1 < ROWS_PER) {              // compile-time: last iter skips
            if (YB) {
                const float* q3 = rp(i + 3);
                const float* q2 = rp(i + 2);
                const float* q1 = rp(i + 1);
                nb2 = q3[j]; nwS = q2[jm]; neS = q2[cjp];
                nww = q1[jmm]; nee = q1[cjpp];
            } else {
                nb2 = pj[j]; nwS = p2[jm]; neS = p2[cjp];
                nww = p1[jmm]; nee = p1[cjpp];
                pj += Wn; p2 += Wn; p1 += Wn;
            }
        }

        float sxi = rd2, sxm = rd2, sxp = rd2;
        bool itop = false, ibot = false;
        if (YB) {
            itop = (i == 0); ibot = (i == Hn - 1);
            sxi = (itop || ibot) ? rd : rd2;
            sxm = (i == 1) ? rd : rd2;        // im == 0
            sxp = (i == Hn - 2) ? rd : rd2;   // ip == Hn-1
        }

        // first derivatives at (i,j)
        const float ex = fmaf(b1 - a1, sxi, SC);
        const float ey = fmaf(e0 - w0, syj, SC);
        // eps_x at rows im/ip (for eps_xx)
        float exn = fmaf(a0 - a2, sxm, SC);
        float exs = fmaf(b2 - a0, sxp, SC);
        if (YB) { if (itop) exn = ex; if (ibot) exs = ex; }
        const float exx = (exs - exn) * sxi;
        // eps_y at cols jm/jp (for eps_yy)
        float eyw = fmaf(a0 - ww, sym, SC);
        const float eye = fmaf(ee - a0, rd2, SC);   // jp never a 2W-grid boundary
        if (jz) eyw = ey;                 // jm == j at left boundary
        const float eyy = (eye - eyw) * syj;
        // eps_xy = Dy(eps_x); the +SC cancels in the difference
        const float exy = ((eS - eN) - (wS - wN)) * (sxi * syj);

        const float t1 = ex * ex, t2 = ey * ey;
        float num = t1 * eyy;
        num = fmaf(t2, exx, num);
        num = fmaf(-2.0f * (ex * ey), exy, num);
        float ev = __builtin_amdgcn_sqrtf(t1 + t2);
        ev = fmaxf(ev, FLOORV);
        const float rv = __builtin_amdgcn_rcpf(ev);
        const float k  = num * (rv * rv) * rv;
        const float at = fast_atan_ratio(ev, a0, rv);
        const float cc = fabsf(k * at) - pi_d;
        float contrib = fmaxf(cc, 0.0f);  // fmax(NaN,0)=0 -> nansum semantics
        if (YB && i >= Hn) contrib = 0.0f;
        acc += contrib;

        // rotate window (register renaming, no real movs after unroll)
        a2 = a1; a1 = a0; a0 = b1; b1 = b2; b2 = nb2;
        wN = w0; w0 = wS; wS = nwS;
        eN = e0; e0 = eS; eS = neS;
        ww = nww; ee = nee;
    }
    return acc;
}

__global__ __launch_bounds__(BLOCK_X, 8) void curve_partial_kernel(
    const float* __restrict__ eps, const float* __restrict__ gs,
    double* __restrict__ partial, int Hn, int Wn)
{
    const int tx = threadIdx.x;
    const int j  = blockIdx.x * BLOCK_X + tx;
    const int i0 = blockIdx.y * ROWS_PER;
    const float d   = gs[0];
    const float rd  = 1.0f / d;
    const float rd2 = 0.5f * rd;

    const int jm  = (j > 0) ? j - 1 : 0;
    const int jmm = (j > 1) ? j - 2 : 0;
    const int jp = j + 1, jpp = j + 2;
    const int cjp  = (jp  < Wn) ? jp  : (2 * Wn - 1 - jp);   // mirror seam
    const int cjpp = (jpp < Wn) ? jpp : (2 * Wn - 1 - jpp);
    const bool jz = (j == 0);
    const float syj = jz ? rd : rd2;
    const float sym = (jm == 0) ? rd : rd2;

    // rows touched by the interior path: i0-2 .. i0+ROWS_PER+1
    const bool yint = (i0 >= 2) && (i0 + ROWS_PER + 1 < Hn);
    const float accf = yint
        ? strip_compute<false>(eps, Hn, Wn, i0, j, jm, jmm, cjp, cjpp, rd, rd2, syj, sym, jz)
        : strip_compute<true >(eps, Hn, Wn, i0, j, jm, jmm, cjp, cjpp, rd, rd2, syj, sym, jz);

    double acc = (double)accf;
    #pragma unroll
    for (int off = 32; off > 0; off >>= 1)
        acc += __shfl_down(acc, off, 64);
    __shared__ double lds[BLOCK_X / 64];
    const int lane = tx & 63, wv = tx >> 6;
    if (lane == 0) lds[wv] = acc;
    __syncthreads();
    if (tx == 0) {
        // plain store — NO device-scope atomics (R2/R3's 3x regression)
        partial[blockIdx.y * gridDim.x + blockIdx.x] =
            lds[0] + lds[1] + lds[2] + lds[3];
    }
}

__global__ __launch_bounds__(256) void curve_finish_kernel(
    const double* __restrict__ partial, int n,
    const float* __restrict__ gs, float* __restrict__ out)
{
    const int tx = threadIdx.x;
    double acc = 0.0;
    for (int idx = tx; idx < n; idx += 256) acc += partial[idx];
    #pragma unroll
    for (int off = 32; off > 0; off >>= 1)
        acc += __shfl_down(acc, off, 64);
    __shared__ double lds[4];
    const int lane = tx & 63, wv = tx >> 6;
    if (lane == 0) lds[wv] = acc;
    __syncthreads();
    if (tx == 0) {
        const double dd = (double)gs[0];
        // x2 for the mirrored half; x d^2 for grid_size^2 (ALPHA=1)
        out[0] = (float)((lds[0] + lds[1] + lds[2] + lds[3]) * 2.0 * dd * dd);
    }
}

extern "C" void kernel_launch(void* const* d_in, const int* in_sizes, int n_in,
                              void* d_out, int out_size, void* d_ws, size_t ws_size,
                              hipStream_t stream) {
    const float* eps = (const float*)d_in[0];
    const float* gs  = (const float*)d_in[1];
    float* out = (float*)d_out;

    const int n = in_sizes[0];
    int Wn = (int)(sqrt((double)n) + 0.5);   // 4096 for 4096x4096
    int Hn = n / Wn;

    const int gx = (Wn + BLOCK_X - 1) / BLOCK_X;     // 16
    const int gy = (Hn + ROWS_PER - 1) / ROWS_PER;   // 256
    double* partial = (double*)d_ws;   // gx*gy slots, ALL written every launch

    curve_partial_kernel<<<dim3(gx, gy), BLOCK_X, 0, stream>>>(eps, gs, partial, Hn, Wn);
    curve_finish_kernel<<<1, 256, 0, stream>>>(partial, gx * gy, gs, out);
}

// Round 3
// 127.550 us; speedup vs baseline: 1.2174x; 1.2174x over previous
//
#include <hip/hip_runtime.h>
#include <math.h>

// fab_penalty_ls_curve — R7: R6 structure, spill-free register budget.
// R6 post-mortem: __launch_bounds__(256,8) => 64-VGPR cap => allocator
// collapsed to 32 VGPRs and spilled the rotating window to scratch.
// Evidence: WRITE_SIZE 0.13MB -> 107MB/dispatch, FETCH +80MB, VALUBusy 32%.
// R7: identical code, cap relaxed to (256,6) (~84 VGPRs). Live set ~44-55
// fits with slack; if actual alloc <=64 the HW still runs 8 waves/SIMD
// (the bound is a cap, not a target).
// Structure (verified absmax 0.0): 1 col/thread, 13-value rolling register
// window, 5 independent prefetch loads per row advance, mirror-half x2,
// plain per-block partial stores -> tiny finish kernel (no device atomics).
// Assumes Wn % BLOCK_X == 0 and Hn % ROWS_PER == 0 (4096x4096 input).

#define BLOCK_X 256
#define ROWS_PER 16

// atan(v / c) with v > 0, given rv ~= 1/v (reused from k = num*rv^3).
// Max abs error ~1e-5 rad; error budget is ~1e3x larger (2% on the sum).
__device__ __forceinline__ float fast_atan_ratio(float v, float c, float rv)
{
    const float rc = __builtin_amdgcn_rcpf(c);
    const float q  = v * rc;        // v/c (sign = sign(c))
    const float iq = c * rv;        // c/v = 1/q, no extra rcp
    const bool  big = fabsf(q) > 1.0f;
    const float t  = big ? iq : q;
    const float s  = t * t;
    float p = fmaf(s, -0.01172120f, 0.05265332f);
    p = fmaf(s, p, -0.11643287f);
    p = fmaf(s, p,  0.19354346f);
    p = fmaf(s, p, -0.33262347f);
    p = fmaf(s, p,  0.99997726f);
    const float at = p * t;
    const float hp = copysignf(1.57079632679f, q);
    return big ? (hp - at) : at;    // atan(q) = sign(q)*pi/2 - atan(1/q), |q|>1
}

// One strip of ROWS_PER points for one column. YB=false: pure interior rows,
// three streaming row pointers. YB=true (first/last gy blocks only): clamped
// row indices + one-sided scales. Window state (13 floats) in named registers:
//   a2 a1 a0 b1 b2 : col j    at rows i-2..i+2
//   wN w0 wS       : col jm   at rows i-1..i+1
//   eN e0 eS       : col cjp  at rows i-1..i+1
//   ww  ee         : cols jmm / cjpp at row i
template<bool YB>
__device__ __forceinline__ float strip_compute(
    const float* __restrict__ eps, int Hn, int Wn, int i0,
    int j, int jm, int jmm, int cjp, int cjpp,
    float rd, float rd2, float syj, float sym, bool jz)
{
    const float SC     = 1e-12f;
    const float FLOORV = (float)(1e-32 / 6.0);
    const float pi_d   = 3.14159265358979323846f / 1.1f;

    auto rp = [&](int t) -> const float* {
        int tt = t;
        if (YB) { tt = tt < 0 ? 0 : tt; tt = tt > Hn - 1 ? Hn - 1 : tt; }
        return eps + (size_t)tt * (size_t)Wn;
    };

    // preload the window for point i0 (13 independent loads)
    float a2 = rp(i0 - 2)[j],   a1 = rp(i0 - 1)[j],  a0 = rp(i0)[j];
    float b1 = rp(i0 + 1)[j],   b2 = rp(i0 + 2)[j];
    float wN = rp(i0 - 1)[jm],  w0 = rp(i0)[jm],     wS = rp(i0 + 1)[jm];
    float eN = rp(i0 - 1)[cjp], e0 = rp(i0)[cjp],    eS = rp(i0 + 1)[cjp];
    float ww = rp(i0)[jmm],     ee = rp(i0)[cjpp];

    // streaming row pointers (interior path only)
    const float* pj = eps + (size_t)(i0 + 3) * (size_t)Wn;  // row i+3 (col j)
    const float* p2 = eps + (size_t)(i0 + 2) * (size_t)Wn;  // row i+2 (jm, cjp)
    const float* p1 = eps + (size_t)(i0 + 1) * (size_t)Wn;  // row i+1 (jmm, cjpp)

    float acc = 0.0f;
    #pragma unroll
    for (int r = 0; r < ROWS_PER; ++r) {
        const int i = i0 + r;

        // prefetch next point's incoming window rows (5 independent loads),
        // issued BEFORE this point's compute so latency hides under the math.
        float nb2 = 0.0f, nwS = 0.0f, neS = 0.0f, nww = 0.0f, nee = 0.0f;
        if (r + 1 < ROWS_PER) {              // compile-time: last iter skips
            if (YB) {
                const float* q3 = rp(i + 3);
                const float* q2 = rp(i + 2);
                const float* q1 = rp(i + 1);
                nb2 = q3[j]; nwS = q2[jm]; neS = q2[cjp];
                nww = q1[jmm]; nee = q1[cjpp];
            } else {
                nb2 = pj[j]; nwS = p2[jm]; neS = p2[cjp];
                nww = p1[jmm]; nee = p1[cjpp];
                pj += Wn; p2 += Wn; p1 += Wn;
            }
        }

        float sxi = rd2, sxm = rd2, sxp = rd2;
        bool itop = false, ibot = false;
        if (YB) {
            itop = (i == 0); ibot = (i == Hn - 1);
            sxi = (itop || ibot) ? rd : rd2;
            sxm = (i == 1) ? rd : rd2;        // im == 0
            sxp = (i == Hn - 2) ? rd : rd2;   // ip == Hn-1
        }

        // first derivatives at (i,j)
        const float ex = fmaf(b1 - a1, sxi, SC);
        const float ey = fmaf(e0 - w0, syj, SC);
        // eps_x at rows im/ip (for eps_xx)
        float exn = fmaf(a0 - a2, sxm, SC);
        float exs = fmaf(b2 - a0, sxp, SC);
        if (YB) { if (itop) exn = ex; if (ibot) exs = ex; }
        const float exx = (exs - exn) * sxi;
        // eps_y at cols jm/jp (for eps_yy)
        float eyw = fmaf(a0 - ww, sym, SC);
        const float eye = fmaf(ee - a0, rd2, SC);   // jp never a 2W-grid boundary
        if (jz) eyw = ey;                 // jm == j at left boundary
        const float eyy = (eye - eyw) * syj;
        // eps_xy = Dy(eps_x); the +SC cancels in the difference
        const float exy = ((eS - eN) - (wS - wN)) * (sxi * syj);

        const float t1 = ex * ex, t2 = ey * ey;
        float num = t1 * eyy;
        num = fmaf(t2, exx, num);
        num = fmaf(-2.0f * (ex * ey), exy, num);
        float ev = __builtin_amdgcn_sqrtf(t1 + t2);
        ev = fmaxf(ev, FLOORV);
        const float rv = __builtin_amdgcn_rcpf(ev);
        const float k  = num * (rv * rv) * rv;
        const float at = fast_atan_ratio(ev, a0, rv);
        const float cc = fabsf(k * at) - pi_d;
        float contrib = fmaxf(cc, 0.0f);  // fmax(NaN,0)=0 -> nansum semantics
        if (YB && i >= Hn) contrib = 0.0f;
        acc += contrib;

        // rotate window (register renaming, no real movs after unroll)
        a2 = a1; a1 = a0; a0 = b1; b1 = b2; b2 = nb2;
        wN = w0; w0 = wS; wS = nwS;
        eN = e0; e0 = eS; eS = neS;
        ww = nww; ee = nee;
    }
    return acc;
}

__global__ __launch_bounds__(BLOCK_X, 6) void curve_partial_kernel(
    const float* __restrict__ eps, const float* __restrict__ gs,
    double* __restrict__ partial, int Hn, int Wn)
{
    const int tx = threadIdx.x;
    const int j  = blockIdx.x * BLOCK_X + tx;
    const int i0 = blockIdx.y * ROWS_PER;
    const float d   = gs[0];
    const float rd  = 1.0f / d;
    const float rd2 = 0.5f * rd;

    const int jm  = (j > 0) ? j - 1 : 0;
    const int jmm = (j > 1) ? j - 2 : 0;
    const int jp = j + 1, jpp = j + 2;
    const int cjp  = (jp  < Wn) ? jp  : (2 * Wn - 1 - jp);   // mirror seam
    const int cjpp = (jpp < Wn) ? jpp : (2 * Wn - 1 - jpp);
    const bool jz = (j == 0);
    const float syj = jz ? rd : rd2;
    const float sym = (jm == 0) ? rd : rd2;

    // rows touched by the interior path: i0-2 .. i0+ROWS_PER+1
    const bool yint = (i0 >= 2) && (i0 + ROWS_PER + 1 < Hn);
    const float accf = yint
        ? strip_compute<false>(eps, Hn, Wn, i0, j, jm, jmm, cjp, cjpp, rd, rd2, syj, sym, jz)
        : strip_compute<true >(eps, Hn, Wn, i0, j, jm, jmm, cjp, cjpp, rd, rd2, syj, sym, jz);

    double acc = (double)accf;
    #pragma unroll
    for (int off = 32; off > 0; off >>= 1)
        acc += __shfl_down(acc, off, 64);
    __shared__ double lds[BLOCK_X / 64];
    const int lane = tx & 63, wv = tx >> 6;
    if (lane == 0) lds[wv] = acc;
    __syncthreads();
    if (tx == 0) {
        // plain store — NO device-scope atomics (R2/R3's 3x regression)
        partial[blockIdx.y * gridDim.x + blockIdx.x] =
            lds[0] + lds[1] + lds[2] + lds[3];
    }
}

__global__ __launch_bounds__(256) void curve_finish_kernel(
    const double* __restrict__ partial, int n,
    const float* __restrict__ gs, float* __restrict__ out)
{
    const int tx = threadIdx.x;
    double acc = 0.0;
    for (int idx = tx; idx < n; idx += 256) acc += partial[idx];
    #pragma unroll
    for (int off = 32; off > 0; off >>= 1)
        acc += __shfl_down(acc, off, 64);
    __shared__ double lds[4];
    const int lane = tx & 63, wv = tx >> 6;
    if (lane == 0) lds[wv] = acc;
    __syncthreads();
    if (tx == 0) {
        const double dd = (double)gs[0];
        // x2 for the mirrored half; x d^2 for grid_size^2 (ALPHA=1)
        out[0] = (float)((lds[0] + lds[1] + lds[2] + lds[3]) * 2.0 * dd * dd);
    }
}

extern "C" void kernel_launch(void* const* d_in, const int* in_sizes, int n_in,
                              void* d_out, int out_size, void* d_ws, size_t ws_size,
                              hipStream_t stream) {
    const float* eps = (const float*)d_in[0];
    const float* gs  = (const float*)d_in[1];
    float* out = (float*)d_out;

    const int n = in_sizes[0];
    int Wn = (int)(sqrt((double)n) + 0.5);   // 4096 for 4096x4096
    int Hn = n / Wn;

    const int gx = (Wn + BLOCK_X - 1) / BLOCK_X;     // 16
    const int gy = (Hn + ROWS_PER - 1) / ROWS_PER;   // 256
    double* partial = (double*)d_ws;   // gx*gy slots, ALL written every launch

    curve_partial_kernel<<<dim3(gx, gy), BLOCK_X, 0, stream>>>(eps, gs, partial, Hn, Wn);
    curve_finish_kernel<<<1, 256, 0, stream>>>(partial, gx * gy, gs, out);
}

// Round 4
// 115.883 us; speedup vs baseline: 1.3399x; 1.1007x over previous
//
#include <hip/hip_runtime.h>
#include <math.h>

// fab_penalty_ls_curve — R8: cap the software-pipeline depth, not the VGPRs.
// R7 post-mortem: full 16x unroll lets the scheduler hoist many iterations'
// independent loads => peak pressure >> cap => allocator spills the rotating
// window (WRITE_SIZE 29MB of scratch at VGPR_Count 40, cap ~80). The lever is
// pipeline depth, not the launch-bounds cap.
// R8: #pragma unroll 4 (max ~20 in-flight loads), plain __launch_bounds__(256)
// (no min-wave VGPR cap), unconditional prefetch with a tightened interior
// predicate (i0+ROWS_PER+2 < Hn) so the last prefetch row stays in bounds.
// Structure otherwise identical to R7 (verified absmax 0.0): 1 col/thread,
// 13-value rolling register window, 5 independent prefetch loads per row,
// mirror-half x2, plain per-block partial stores -> tiny finish kernel.
// Assumes Wn % BLOCK_X == 0 (4096x4096 input).

#define BLOCK_X 256
#define ROWS_PER 16

// atan(v / c) with v > 0, given rv ~= 1/v (reused from k = num*rv^3).
// Max abs error ~1e-5 rad; error budget is ~1e3x larger (2% on the sum).
__device__ __forceinline__ float fast_atan_ratio(float v, float c, float rv)
{
    const float rc = __builtin_amdgcn_rcpf(c);
    const float q  = v * rc;        // v/c (sign = sign(c))
    const float iq = c * rv;        // c/v = 1/q, no extra rcp
    const bool  big = fabsf(q) > 1.0f;
    const float t  = big ? iq : q;
    const float s  = t * t;
    float p = fmaf(s, -0.01172120f, 0.05265332f);
    p = fmaf(s, p, -0.11643287f);
    p = fmaf(s, p,  0.19354346f);
    p = fmaf(s, p, -0.33262347f);
    p = fmaf(s, p,  0.99997726f);
    const float at = p * t;
    const float hp = copysignf(1.57079632679f, q);
    return big ? (hp - at) : at;    // atan(q) = sign(q)*pi/2 - atan(1/q), |q|>1
}

// One strip of ROWS_PER points for one column. YB=false: pure interior rows,
// three streaming row pointers. YB=true (first/last gy strips only): clamped
// row indices + one-sided scales. Window state (13 floats) in loop-carried
// scalars (no dynamic indexing => registers):
//   a2 a1 a0 b1 b2 : col j    at rows i-2..i+2
//   wN w0 wS       : col jm   at rows i-1..i+1
//   eN e0 eS       : col cjp  at rows i-1..i+1
//   ww  ee         : cols jmm / cjpp at row i
template<bool YB>
__device__ __forceinline__ float strip_compute(
    const float* __restrict__ eps, int Hn, int Wn, int i0,
    int j, int jm, int jmm, int cjp, int cjpp,
    float rd, float rd2, float syj, float sym, bool jz)
{
    const float SC     = 1e-12f;
    const float FLOORV = (float)(1e-32 / 6.0);
    const float pi_d   = 3.14159265358979323846f / 1.1f;

    auto rp = [&](int t) -> const float* {
        int tt = t;
        if (YB) { tt = tt < 0 ? 0 : tt; tt = tt > Hn - 1 ? Hn - 1 : tt; }
        return eps + (size_t)tt * (size_t)Wn;
    };

    // preload the window for point i0 (13 independent loads)
    float a2 = rp(i0 - 2)[j],   a1 = rp(i0 - 1)[j],  a0 = rp(i0)[j];
    float b1 = rp(i0 + 1)[j],   b2 = rp(i0 + 2)[j];
    float wN = rp(i0 - 1)[jm],  w0 = rp(i0)[jm],     wS = rp(i0 + 1)[jm];
    float eN = rp(i0 - 1)[cjp], e0 = rp(i0)[cjp],    eS = rp(i0 + 1)[cjp];
    float ww = rp(i0)[jmm],     ee = rp(i0)[cjpp];

    // streaming row pointers (interior path only)
    const float* pj = eps + (size_t)(i0 + 3) * (size_t)Wn;  // row i+3 (col j)
    const float* p2 = eps + (size_t)(i0 + 2) * (size_t)Wn;  // row i+2 (jm, cjp)
    const float* p1 = eps + (size_t)(i0 + 1) * (size_t)Wn;  // row i+1 (jmm, cjpp)

    float acc = 0.0f;
    #pragma unroll 4
    for (int r = 0; r < ROWS_PER; ++r) {
        const int i = i0 + r;

        // prefetch next point's incoming window rows (5 independent loads),
        // issued BEFORE this point's compute so latency hides under the math.
        // Unconditional: interior predicate guarantees row i+3 <= Hn-1; the
        // last iteration's values are simply discarded at loop exit.
        float nb2, nwS, neS, nww, nee;
        if (YB) {
            const float* q3 = rp(i + 3);
            const float* q2 = rp(i + 2);
            const float* q1 = rp(i + 1);
            nb2 = q3[j]; nwS = q2[jm]; neS = q2[cjp];
            nww = q1[jmm]; nee = q1[cjpp];
        } else {
            nb2 = pj[j]; nwS = p2[jm]; neS = p2[cjp];
            nww = p1[jmm]; nee = p1[cjpp];
            pj += Wn; p2 += Wn; p1 += Wn;
        }

        float sxi = rd2, sxm = rd2, sxp = rd2;
        bool itop = false, ibot = false;
        if (YB) {
            itop = (i == 0); ibot = (i == Hn - 1);
            sxi = (itop || ibot) ? rd : rd2;
            sxm = (i == 1) ? rd : rd2;        // im == 0
            sxp = (i == Hn - 2) ? rd : rd2;   // ip == Hn-1
        }

        // first derivatives at (i,j)
        const float ex = fmaf(b1 - a1, sxi, SC);
        const float ey = fmaf(e0 - w0, syj, SC);
        // eps_x at rows im/ip (for eps_xx)
        float exn = fmaf(a0 - a2, sxm, SC);
        float exs = fmaf(b2 - a0, sxp, SC);
        if (YB) { if (itop) exn = ex; if (ibot) exs = ex; }
        const float exx = (exs - exn) * sxi;
        // eps_y at cols jm/jp (for eps_yy)
        float eyw = fmaf(a0 - ww, sym, SC);
        const float eye = fmaf(ee - a0, rd2, SC);   // jp never a 2W-grid boundary
        if (jz) eyw = ey;                 // jm == j at left boundary
        const float eyy = (eye - eyw) * syj;
        // eps_xy = Dy(eps_x); the +SC cancels in the difference
        const float exy = ((eS - eN) - (wS - wN)) * (sxi * syj);

        const float t1 = ex * ex, t2 = ey * ey;
        float num = t1 * eyy;
        num = fmaf(t2, exx, num);
        num = fmaf(-2.0f * (ex * ey), exy, num);
        float ev = __builtin_amdgcn_sqrtf(t1 + t2);
        ev = fmaxf(ev, FLOORV);
        const float rv = __builtin_amdgcn_rcpf(ev);
        const float k  = num * (rv * rv) * rv;
        const float at = fast_atan_ratio(ev, a0, rv);
        const float cc = fabsf(k * at) - pi_d;
        float contrib = fmaxf(cc, 0.0f);  // fmax(NaN,0)=0 -> nansum semantics
        if (YB && i >= Hn) contrib = 0.0f;
        acc += contrib;

        // rotate window (loop-carried scalars; partial unroll => a few movs)
        a2 = a1; a1 = a0; a0 = b1; b1 = b2; b2 = nb2;
        wN = w0; w0 = wS; wS = nwS;
        eN = e0; e0 = eS; eS = neS;
        ww = nww; ee = nee;
    }
    return acc;
}

__global__ __launch_bounds__(BLOCK_X) void curve_partial_kernel(
    const float* __restrict__ eps, const float* __restrict__ gs,
    double* __restrict__ partial, int Hn, int Wn)
{
    const int tx = threadIdx.x;
    const int j  = blockIdx.x * BLOCK_X + tx;
    const int i0 = blockIdx.y * ROWS_PER;
    const float d   = gs[0];
    const float rd  = 1.0f / d;
    const float rd2 = 0.5f * rd;

    const int jm  = (j > 0) ? j - 1 : 0;
    const int jmm = (j > 1) ? j - 2 : 0;
    const int jp = j + 1, jpp = j + 2;
    const int cjp  = (jp  < Wn) ? jp  : (2 * Wn - 1 - jp);   // mirror seam
    const int cjpp = (jpp < Wn) ? jpp : (2 * Wn - 1 - jpp);
    const bool jz = (j == 0);
    const float syj = jz ? rd : rd2;
    const float sym = (jm == 0) ? rd : rd2;

    // interior path touches rows i0-2 .. i0+ROWS_PER+2 (incl. last prefetch)
    const bool yint = (i0 >= 2) && (i0 + ROWS_PER + 2 < Hn);
    const float accf = yint
        ? strip_compute<false>(eps, Hn, Wn, i0, j, jm, jmm, cjp, cjpp, rd, rd2, syj, sym, jz)
        : strip_compute<true >(eps, Hn, Wn, i0, j, jm, jmm, cjp, cjpp, rd, rd2, syj, sym, jz);

    double acc = (double)accf;
    #pragma unroll
    for (int off = 32; off > 0; off >>= 1)
        acc += __shfl_down(acc, off, 64);
    __shared__ double lds[BLOCK_X / 64];
    const int lane = tx & 63, wv = tx >> 6;
    if (lane == 0) lds[wv] = acc;
    __syncthreads();
    if (tx == 0) {
        // plain store — NO device-scope atomics (R2/R3's 3x regression)
        partial[blockIdx.y * gridDim.x + blockIdx.x] =
            lds[0] + lds[1] + lds[2] + lds[3];
    }
}

__global__ __launch_bounds__(256) void curve_finish_kernel(
    const double* __restrict__ partial, int n,
    const float* __restrict__ gs, float* __restrict__ out)
{
    const int tx = threadIdx.x;
    double acc = 0.0;
    for (int idx = tx; idx < n; idx += 256) acc += partial[idx];
    #pragma unroll
    for (int off = 32; off > 0; off >>= 1)
        acc += __shfl_down(acc, off, 64);
    __shared__ double lds[4];
    const int lane = tx & 63, wv = tx >> 6;
    if (lane == 0) lds[wv] = acc;
    __syncthreads();
    if (tx == 0) {
        const double dd = (double)gs[0];
        // x2 for the mirrored half; x d^2 for grid_size^2 (ALPHA=1)
        out[0] = (float)((lds[0] + lds[1] + lds[2] + lds[3]) * 2.0 * dd * dd);
    }
}

extern "C" void kernel_launch(void* const* d_in, const int* in_sizes, int n_in,
                              void* d_out, int out_size, void* d_ws, size_t ws_size,
                              hipStream_t stream) {
    const float* eps = (const float*)d_in[0];
    const float* gs  = (const float*)d_in[1];
    float* out = (float*)d_out;

    const int n = in_sizes[0];
    int Wn = (int)(sqrt((double)n) + 0.5);   // 4096 for 4096x4096
    int Hn = n / Wn;

    const int gx = (Wn + BLOCK_X - 1) / BLOCK_X;     // 16
    const int gy = (Hn + ROWS_PER - 1) / ROWS_PER;   // 256
    double* partial = (double*)d_ws;   // gx*gy slots, ALL written every launch

    curve_partial_kernel<<<dim3(gx, gy), BLOCK_X, 0, stream>>>(eps, gs, partial, Hn, Wn);
    curve_finish_kernel<<<1, 256, 0, stream>>>(partial, gx * gy, gs, out);
}

// Round 6
// 112.342 us; speedup vs baseline: 1.3822x; 1.0315x over previous
//
#include <hip/hip_runtime.h>
#include <math.h>

// fab_penalty_ls_curve — R9b: resubmit of R9 (round-5 bench was an infra
// failure: "MI355X container failed twice", no counters). Kernel re-audited:
// bounds, alignment, edge semantics, workspace all verified — no defect found.
//
// R9: packed-fp32 math + column-pair load sharing.
// R8 post-mortem (confirmed): depth-4 pipeline killed the spills (WRITE 29MB
// -> 128KB), partial 48->42us, VALU-issue-bound at 64% busy, HBM 13%.
// R9 levers: (1) gfx950 v_pk_*_f32 doubles fp32 issue rate — express the
// per-point math as float2 ext-vectors (clang lowers to VOP3P packed);
// (2) each thread owns an even column pair (j0, j0+1): per row advance,
// 3 aligned float2 loads (cols j0-2..j0+3) feed TWO points => 1.5 loads/pt
// (was 5). Per-component op order identical to R8 (absmax 0.0 lineage).
// Mirror seam / left clamp stay register substitutions ({c.y,c.x} / {c.x,c.x}).
// X-edge blocks = separate template instantiation (interior pays zero).
// Y-boundary strips (2/256) reuse R8's verified scalar path per column.
// Spill tripwire: WRITE_SIZE must stay ~128KB. __launch_bounds__(256,4)
// caps VGPR at 128 — ABOVE expected demand (~80-100); R6/R7 lesson: never
// cap below natural demand. Assumes Wn % (2*BLOCK_X) == 0 (4096x4096).

#define BLOCK_X 256
#define ROWS_PER 16

typedef float f32x2 __attribute__((ext_vector_type(2)));

__device__ __forceinline__ f32x2 mk2(float a, float b) { f32x2 v; v.x = a; v.y = b; return v; }
__device__ __forceinline__ f32x2 sp2(float a) { return mk2(a, a); }

#if __has_builtin(__builtin_elementwise_fma)
__device__ __forceinline__ f32x2 fma2(f32x2 a, f32x2 b, f32x2 c) { return __builtin_elementwise_fma(a, b, c); }
#else
__device__ __forceinline__ f32x2 fma2(f32x2 a, f32x2 b, f32x2 c) { return mk2(fmaf(a.x, b.x, c.x), fmaf(a.y, b.y, c.y)); }
#endif
#if __has_builtin(__builtin_elementwise_max)
__device__ __forceinline__ f32x2 max2(f32x2 a, f32x2 b) { return __builtin_elementwise_max(a, b); }
#else
__device__ __forceinline__ f32x2 max2(f32x2 a, f32x2 b) { return mk2(fmaxf(a.x, b.x), fmaxf(a.y, b.y)); }
#endif
__device__ __forceinline__ f32x2 abs2(f32x2 a) { return mk2(fabsf(a.x), fabsf(a.y)); }

// ---- scalar helpers (YB path + per-component transcendentals) ----

// atan(v / c) with v > 0, given rv ~= 1/v. Max abs err ~1e-5 rad.
__device__ __forceinline__ float fast_atan_ratio(float v, float c, float rv)
{
    const float rc = __builtin_amdgcn_rcpf(c);
    const float q  = v * rc;
    const float iq = c * rv;
    const bool  big = fabsf(q) > 1.0f;
    const float t  = big ? iq : q;
    const float s  = t * t;
    float p = fmaf(s, -0.01172120f, 0.05265332f);
    p = fmaf(s, p, -0.11643287f);
    p = fmaf(s, p,  0.19354346f);
    p = fmaf(s, p, -0.33262347f);
    p = fmaf(s, p,  0.99997726f);
    const float at = p * t;
    const float hp = copysignf(1.57079632679f, q);
    return big ? (hp - at) : at;
}

// packed variant: componentwise identical op sequence
__device__ __forceinline__ f32x2 fast_atan_ratio2(f32x2 v, f32x2 c, f32x2 rvv)
{
    const f32x2 rc = mk2(__builtin_amdgcn_rcpf(c.x), __builtin_amdgcn_rcpf(c.y));
    const f32x2 q  = v * rc;
    const f32x2 iq = c * rvv;
    const bool big0 = fabsf(q.x) > 1.0f, big1 = fabsf(q.y) > 1.0f;
    const f32x2 t = mk2(big0 ? iq.x : q.x, big1 ? iq.y : q.y);
    const f32x2 s = t * t;
    f32x2 p = fma2(s, sp2(-0.01172120f), sp2(0.05265332f));
    p = fma2(s, p, sp2(-0.11643287f));
    p = fma2(s, p, sp2( 0.19354346f));
    p = fma2(s, p, sp2(-0.33262347f));
    p = fma2(s, p, sp2( 0.99997726f));
    const f32x2 at = p * t;
    const float hp0 = copysignf(1.57079632679f, q.x);
    const float hp1 = copysignf(1.57079632679f, q.y);
    return mk2(big0 ? (hp0 - at.x) : at.x, big1 ? (hp1 - at.y) : at.y);
}

// Load the 6-wide window (cols j0-2..j0+3) of one row as 3 aligned float2.
// XE blocks: clamp wing addresses in-bounds, then substitute values:
//   left  (j0==0):     cols -2,-1 clamp to col 0      -> {c.x, c.x}
//   right (j0+2==Wn):  cols Wn,Wn+1 mirror to Wn-1..  -> {c.y, c.x}
template<bool XE>
__device__ __forceinline__ void load6(const float* __restrict__ rowp, int j0,
                                      bool left, bool right,
                                      f32x2& m, f32x2& c, f32x2& p)
{
    c = *reinterpret_cast<const f32x2*>(rowp + j0);
    if (XE) {
        const float* ma = rowp + (left  ? j0 : j0 - 2);
        const float* pa = rowp + (right ? j0 : j0 + 2);
        m = *reinterpret_cast<const f32x2*>(ma);
        p = *reinterpret_cast<const f32x2*>(pa);
        if (left)  m = mk2(c.x, c.x);
        if (right) p = mk2(c.y, c.x);
    } else {
        m = *reinterpret_cast<const f32x2*>(rowp + j0 - 2);
        p = *reinterpret_cast<const f32x2*>(rowp + j0 + 2);
    }
}

// Packed interior-Y strip: rows i0..i0+ROWS_PER-1, cols {j0, j0+1}.
// Window: A = row i-2 center pair; B/C/D/E = rows i-1..i+2, 3 float2 each.
template<bool XE>
__device__ __forceinline__ f32x2 strip_packed(
    const float* __restrict__ eps, int Wn, int i0, int j0,
    bool left, bool right, float rd2, f32x2 syjv, f32x2 symv)
{
    const f32x2 SC2    = sp2(1e-12f);
    const float FLOORV = (float)(1e-32 / 6.0);
    const float pi_d   = 3.14159265358979323846f / 1.1f;

    const float* r0 = eps + (size_t)(i0 - 2) * (size_t)Wn;
    f32x2 A = *reinterpret_cast<const f32x2*>(r0 + j0);
    f32x2 Bm, Bc, Bp, Cm, Cc, Cp, Dm, Dc, Dp, Em, Ec, Ep;
    load6<XE>(r0 + (size_t)Wn,     j0, left, right, Bm, Bc, Bp);
    load6<XE>(r0 + (size_t)2 * Wn, j0, left, right, Cm, Cc, Cp);
    load6<XE>(r0 + (size_t)3 * Wn, j0, left, right, Dm, Dc, Dp);
    load6<XE>(r0 + (size_t)4 * Wn, j0, left, right, Em, Ec, Ep);
    const float* pr = r0 + (size_t)5 * Wn;   // row i0+3

    f32x2 acc = sp2(0.0f);
    #pragma unroll 4
    for (int r = 0; r < ROWS_PER; ++r) {
        // prefetch row i+3 (3 independent float2 loads) before the compute
        f32x2 Fm, Fc, Fp;
        load6<XE>(pr, j0, left, right, Fm, Fc, Fp);
        pr += Wn;

        // interior-Y: sxi = sxm = sxp = rd2
        const f32x2 ex  = fma2(Dc - Bc, sp2(rd2), SC2);
        const f32x2 Cl1 = mk2(Cm.y, Cc.x), Cr1 = mk2(Cc.y, Cp.x);
        const f32x2 ey  = fma2(Cr1 - Cl1, syjv, SC2);
        const f32x2 exn = fma2(Cc - A,  sp2(rd2), SC2);
        const f32x2 exs = fma2(Ec - Cc, sp2(rd2), SC2);
        const f32x2 exx = (exs - exn) * rd2;
        f32x2 eyw = fma2(Cc - Cm, symv, SC2);
        const f32x2 eye = fma2(Cp - Cc, sp2(rd2), SC2);
        if (XE) { if (left) eyw.x = ey.x; }       // j==0: eps_y[jm] == eps_y[j]
        const f32x2 eyy = (eye - eyw) * syjv;
        const f32x2 Bl1 = mk2(Bm.y, Bc.x), Br1 = mk2(Bc.y, Bp.x);
        const f32x2 Dl1 = mk2(Dm.y, Dc.x), Dr1 = mk2(Dc.y, Dp.x);
        const f32x2 exy = ((Dr1 - Br1) - (Dl1 - Bl1)) * (syjv * rd2);

        const f32x2 t1 = ex * ex, t2 = ey * ey;
        f32x2 num = t1 * eyy;
        num = fma2(t2, exx, num);
        num = fma2((ex * ey) * -2.0f, exy, num);
        const f32x2 ssum = t1 + t2;
        float ev0 = __builtin_amdgcn_sqrtf(ssum.x);
        float ev1 = __builtin_amdgcn_sqrtf(ssum.y);
        ev0 = fmaxf(ev0, FLOORV);
        ev1 = fmaxf(ev1, FLOORV);
        const f32x2 evv = mk2(ev0, ev1);
        const f32x2 rvv = mk2(__builtin_amdgcn_rcpf(ev0), __builtin_amdgcn_rcpf(ev1));
        const f32x2 k   = num * (rvv * rvv) * rvv;
        const f32x2 at  = fast_atan_ratio2(evv, Cc, rvv);
        const f32x2 cc  = abs2(k * at) - sp2(pi_d);
        acc = acc + max2(cc, sp2(0.0f));          // maxnum(NaN,0)=0 -> nansum

        // rotate window (named f32x2 scalars; unroll-4 => few real movs)
        A  = Bc;
        Bm = Cm; Bc = Cc; Bp = Cp;
        Cm = Dm; Cc = Dc; Cp = Dp;
        Dm = Em; Dc = Ec; Dp = Ep;
        Em = Fm; Ec = Fc; Ep = Fp;
    }
    return acc;
}

// R8's verified scalar Y-boundary strip (YB hardwired true), one column.
__device__ float strip_scalar_yb(const float* __restrict__ eps, int Hn, int Wn,
                                 int i0, int j, float rd, float rd2)
{
    const float SC     = 1e-12f;
    const float FLOORV = (float)(1e-32 / 6.0);
    const float pi_d   = 3.14159265358979323846f / 1.1f;

    const int jm  = (j > 0) ? j - 1 : 0;
    const int jmm = (j > 1) ? j - 2 : 0;
    const int jp = j + 1, jpp = j + 2;
    const int cjp  = (jp  < Wn) ? jp  : (2 * Wn - 1 - jp);
    const int cjpp = (jpp < Wn) ? jpp : (2 * Wn - 1 - jpp);
    const bool jz = (j == 0);
    const float syj = jz ? rd : rd2;
    const float sym = (jm == 0) ? rd : rd2;

    auto rp = [&](int t) -> const float* {
        int tt = t < 0 ? 0 : t;
        tt = tt > Hn - 1 ? Hn - 1 : tt;
        return eps + (size_t)tt * (size_t)Wn;
    };

    float a2 = rp(i0 - 2)[j],   a1 = rp(i0 - 1)[j],  a0 = rp(i0)[j];
    float b1 = rp(i0 + 1)[j],   b2 = rp(i0 + 2)[j];
    float wN = rp(i0 - 1)[jm],  w0 = rp(i0)[jm],     wS = rp(i0 + 1)[jm];
    float eN = rp(i0 - 1)[cjp], e0 = rp(i0)[cjp],    eS = rp(i0 + 1)[cjp];
    float ww = rp(i0)[jmm],     ee = rp(i0)[cjpp];

    float acc = 0.0f;
    #pragma unroll 4
    for (int r = 0; r < ROWS_PER; ++r) {
        const int i = i0 + r;
        const float* q3 = rp(i + 3);
        const float* q2 = rp(i + 2);
        const float* q1 = rp(i + 1);
        const float nb2 = q3[j], nwS = q2[jm], neS = q2[cjp];
        const float nww = q1[jmm], nee = q1[cjpp];

        const bool itop = (i == 0), ibot = (i == Hn - 1);
        const float sxi = (itop || ibot) ? rd : rd2;
        const float sxm = (i == 1) ? rd : rd2;
        const float sxp = (i == Hn - 2) ? rd : rd2;

        const float ex = fmaf(b1 - a1, sxi, SC);
        const float ey = fmaf(e0 - w0, syj, SC);
        float exn = fmaf(a0 - a2, sxm, SC);
        float exs = fmaf(b2 - a0, sxp, SC);
        if (itop) exn = ex;
        if (ibot) exs = ex;
        const float exx = (exs - exn) * sxi;
        float eyw = fmaf(a0 - ww, sym, SC);
        const float eye = fmaf(ee - a0, rd2, SC);
        if (jz) eyw = ey;
        const float eyy = (eye - eyw) * syj;
        const float exy = ((eS - eN) - (wS - wN)) * (sxi * syj);

        const float t1 = ex * ex, t2 = ey * ey;
        float num = t1 * eyy;
        num = fmaf(t2, exx, num);
        num = fmaf(-2.0f * (ex * ey), exy, num);
        float ev = __builtin_amdgcn_sqrtf(t1 + t2);
        ev = fmaxf(ev, FLOORV);
        const float rv = __builtin_amdgcn_rcpf(ev);
        const float k  = num * (rv * rv) * rv;
        const float at = fast_atan_ratio(ev, a0, rv);
        const float ccv = fabsf(k * at) - pi_d;
        float contrib = fmaxf(ccv, 0.0f);
        if (i >= Hn) contrib = 0.0f;
        acc += contrib;

        a2 = a1; a1 = a0; a0 = b1; b1 = b2; b2 = nb2;
        wN = w0; w0 = wS; wS = nwS;
        eN = e0; e0 = eS; eS = neS;
        ww = nww; ee = nee;
    }
    return acc;
}

__global__ __launch_bounds__(BLOCK_X, 4) void curve_partial_kernel(
    const float* __restrict__ eps, const float* __restrict__ gs,
    double* __restrict__ partial, int Hn, int Wn)
{
    const int tx = threadIdx.x;
    const int j0 = (blockIdx.x * BLOCK_X + tx) * 2;
    const int i0 = blockIdx.y * ROWS_PER;
    const float d   = gs[0];
    const float rd  = 1.0f / d;
    const float rd2 = 0.5f * rd;
    const bool left  = (j0 == 0);
    const bool right = (j0 + 2 == Wn);

    // interior path touches rows i0-2 .. i0+ROWS_PER+2 (incl. last prefetch)
    const bool yint = (i0 >= 2) && (i0 + ROWS_PER + 2 < Hn);

    f32x2 accv;
    if (yint) {
        const f32x2 syjv = left ? mk2(rd,  rd2) : sp2(rd2);  // col0: fwd diff
        const f32x2 symv = left ? mk2(rd2, rd ) : sp2(rd2);  // col1: jm==0
        const bool xe = (blockIdx.x == 0) || (blockIdx.x == gridDim.x - 1);
        accv = xe
            ? strip_packed<true >(eps, Wn, i0, j0, left, right, rd2, syjv, symv)
            : strip_packed<false>(eps, Wn, i0, j0, left, right, rd2, syjv, symv);
    } else {
        accv.x = strip_scalar_yb(eps, Hn, Wn, i0, j0,     rd, rd2);
        accv.y = strip_scalar_yb(eps, Hn, Wn, i0, j0 + 1, rd, rd2);
    }

    double acc = (double)accv.x + (double)accv.y;
    #pragma unroll
    for (int off = 32; off > 0; off >>= 1)
        acc += __shfl_down(acc, off, 64);
    __shared__ double lds[BLOCK_X / 64];
    const int lane = tx & 63, wv = tx >> 6;
    if (lane == 0) lds[wv] = acc;
    __syncthreads();
    if (tx == 0) {
        // plain store — NO device-scope atomics (R2/R3's 3x regression)
        partial[blockIdx.y * gridDim.x + blockIdx.x] =
            lds[0] + lds[1] + lds[2] + lds[3];
    }
}

__global__ __launch_bounds__(256) void curve_finish_kernel(
    const double* __restrict__ partial, int n,
    const float* __restrict__ gs, float* __restrict__ out)
{
    const int tx = threadIdx.x;
    double acc = 0.0;
    for (int idx = tx; idx < n; idx += 256) acc += partial[idx];
    #pragma unroll
    for (int off = 32; off > 0; off >>= 1)
        acc += __shfl_down(acc, off, 64);
    __shared__ double lds[4];
    const int lane = tx & 63, wv = tx >> 6;
    if (lane == 0) lds[wv] = acc;
    __syncthreads();
    if (tx == 0) {
        const double dd = (double)gs[0];
        // x2 for the mirrored half; x d^2 for grid_size^2 (ALPHA=1)
        out[0] = (float)((lds[0] + lds[1] + lds[2] + lds[3]) * 2.0 * dd * dd);
    }
}

extern "C" void kernel_launch(void* const* d_in, const int* in_sizes, int n_in,
                              void* d_out, int out_size, void* d_ws, size_t ws_size,
                              hipStream_t stream) {
    const float* eps = (const float*)d_in[0];
    const float* gs  = (const float*)d_in[1];
    float* out = (float*)d_out;

    const int n = in_sizes[0];
    int Wn = (int)(sqrt((double)n) + 0.5);   // 4096 for 4096x4096
    int Hn = n / Wn;

    const int gx = Wn / (BLOCK_X * 2);               // 8 (assumes divisible)
    const int gy = (Hn + ROWS_PER - 1) / ROWS_PER;   // 256
    double* partial = (double*)d_ws;   // gx*gy slots, ALL written every launch

    curve_partial_kernel<<<dim3(gx, gy), BLOCK_X, 0, stream>>>(eps, gs, partial, Hn, Wn);
    curve_finish_kernel<<<1, 256, 0, stream>>>(partial, gx * gy, gs, out);
}